// Round 14
// baseline (132.373 us; speedup 1.0000x reference)
//
#include <hip/hip_runtime.h>
#include <math.h>

// SparseAttention: E=8 experts x CAP=4 routed batches, full attention over
// [H=16, S=512, D=64] with key mask bias. fp32 in/out, fp16 MFMA compute.
// R14 = R13 with (a) V in TWO [64x64] SW64 buffers (R13's SW128 V-write was
// an 8-way bank conflict — 2.1M; SW64 pattern measured 0 in R12), and
// (b) two-half software pipeline: QK0 -> SM0 -> QK1 -> PV0 -> SM1 -> PV1
// (SM1 VALU overlaps PV0 MFMAs; QK1 MFMAs overlap SM0 drain). To keep
// VGPR < 128 (waves/SIMD halve at 128 — m69), l is summed via VALU in SM
// (drops ones-operand + lacc MFMAs; epilogue shuffle redistribution back).
// Keeps: in-register P->PV key permutation, 512-thr blocks, 128-key rounds,
// sibling-XCD swizzle, bias-in-LDS, fixed-ref softmax, setprio.

typedef _Float16 f16x8 __attribute__((ext_vector_type(8)));
typedef _Float16 f16x2 __attribute__((ext_vector_type(2)));
typedef float    f32x4 __attribute__((ext_vector_type(4)));

#define MFMA16(a, b, c) __builtin_amdgcn_mfma_f32_16x16x32_f16((a), (b), (c), 0, 0, 0)

constexpr int Hh = 16;
constexpr int Ss = 512;
constexpr int Dd = 64;
constexpr int QB = 256;       // query rows per workgroup (8 waves x 32)
constexpr int KVR = 128;      // keys staged per barrier round
constexpr int NR = Ss / KVR;  // 4 rounds
constexpr float QS = 0.125f * 1.44269504088896f;      // scale*log2e in Q
constexpr float BM = 1000000.0f * 1.44269504088896f;  // penalty * log2e

union U8 { f16x8 v; f16x2 h[4]; };

// Swizzled half-index in a [rows][64 half cols] tile (row stride 128B).
__device__ __forceinline__ int SW64(int row, int col) {
  return row * 64 + (col ^ ((row & 7) << 3));
}

__device__ __forceinline__ f16x2 pkrtz(float a, float b) {
  auto t = __builtin_amdgcn_cvt_pkrtz(a, b);
  return *(f16x2*)&t;
}

__global__ __launch_bounds__(512) void sparse_attn_kernel(
    const float* __restrict__ Q, const float* __restrict__ K,
    const float* __restrict__ V, const int* __restrict__ idx,
    const float* __restrict__ mask, float* __restrict__ out) {
  const int tid  = threadIdx.x;
  const int lane = tid & 63;
  const int wv   = tid >> 6;        // wave 0..7
  const int r    = lane & 15;       // MFMA 16-lane index
  const int g    = lane >> 4;       // MFMA 4-group 0..3

  // Sibling-XCD swizzle (bijective): the 2 qb siblings of one (ec,h) share
  // phys%8 -> same XCD, 8 dispatch slots apart -> K/V L2-deduped.
  const int phys = blockIdx.x;       // 1024
  const int G    = (phys & 7) | ((phys >> 4) << 3);
  const int qb   = (phys >> 3) & 1;
  const int h    = G & 15;
  const int ec   = G >> 4;
  const int b    = idx[ec];

  __shared__ _Float16 Ks[128 * 64];     // [key 0..127][dim] SW64
  __shared__ _Float16 VTs[2][64 * 64];  // [half][dim][perm-key] SW64
  __shared__ float    biasS[Ss];        // precomputed bias row (m*BM - BM)

  const size_t bh = ((size_t)b * Hh + h) * (size_t)Ss * Dd;
  const float* Qb = Q + bh;
  const float* Kb = K + bh;
  const float* Vb = V + bh;
  const float* mrow = mask + (size_t)b * Ss;

  // ---- prologue: precompute bias row into LDS (1 float/thread) ----
  biasS[tid] = mrow[tid] * BM - BM;

  const int q0 = qb * QB + wv * 32;

  // ---- Q fragments, pre-scaled (B-operand: col=lane%16 -> q row) ----
  f16x8 qf[2][2];
#pragma unroll
  for (int mi = 0; mi < 2; ++mi)
#pragma unroll
    for (int kk = 0; kk < 2; ++kk) {
      const float* qp = Qb + (size_t)(q0 + mi * 16 + r) * Dd + kk * 32 + g * 8;
      float4 x0 = *(const float4*)qp;
      float4 x1 = *(const float4*)(qp + 4);
      U8 u;
      u.h[0] = pkrtz(x0.x * QS, x0.y * QS);
      u.h[1] = pkrtz(x0.z * QS, x0.w * QS);
      u.h[2] = pkrtz(x1.x * QS, x1.y * QS);
      u.h[3] = pkrtz(x1.z * QS, x1.w * QS);
      qf[mi][kk] = u.v;
    }

  f32x4 oacc[2][4];
#pragma unroll
  for (int mi = 0; mi < 2; ++mi)
#pragma unroll
    for (int nj = 0; nj < 4; ++nj) oacc[mi][nj] = (f32x4){0.f, 0.f, 0.f, 0.f};
  float l_acc[2] = {0.f, 0.f};   // lane-partial softmax denominator

  // ---- prefetch registers (round t+1 in flight while computing round t) ----
  float4 kx0[2], kx1[2];
  float  vv[2][8];

  // K map: j=it*512+tid -> krow=j>>3 (0..127), dg8=j&7 (16B group).
  // V map: thread (oct=tid>>6, dim=tid&63), half=it; VTs[it] col
  // kk*32+8*g2+j holds phys key it*64+(kk+2*(j>>2))*16+g2*4+(j&3)
  // — matches QK^T D-layout per half (P stays in registers).
#define KV_ISSUE(KV0)                                                        \
  {                                                                          \
    _Pragma("unroll")                                                        \
    for (int it = 0; it < 2; ++it) {                                         \
      int j = it * 512 + tid;                                                \
      const float* kp_ = Kb + (size_t)((KV0) + (j >> 3)) * Dd + (j & 7) * 8; \
      kx0[it] = *(const float4*)kp_;                                         \
      kx1[it] = *(const float4*)(kp_ + 4);                                   \
    }                                                                        \
    _Pragma("unroll")                                                        \
    for (int it = 0; it < 2; ++it) {                                         \
      int oct = tid >> 6;                                                    \
      int kb1 = (oct >> 2) * 16 + (oct & 3) * 4 + it * 64;                   \
      const float* vp = Vb + (size_t)((KV0) + kb1) * Dd + (tid & 63);        \
      _Pragma("unroll")                                                      \
      for (int jj = 0; jj < 4; ++jj) {                                       \
        vv[it][jj]     = vp[(size_t)jj * Dd];                                \
        vv[it][jj + 4] = vp[(size_t)(jj + 32) * Dd];                         \
      }                                                                      \
    }                                                                        \
  }

#define STAGE_WRITE()                                                        \
  {                                                                          \
    _Pragma("unroll")                                                        \
    for (int it = 0; it < 2; ++it) {                                         \
      int j = it * 512 + tid;                                                \
      U8 u;                                                                  \
      u.h[0] = pkrtz(kx0[it].x, kx0[it].y);                                  \
      u.h[1] = pkrtz(kx0[it].z, kx0[it].w);                                  \
      u.h[2] = pkrtz(kx1[it].x, kx1[it].y);                                  \
      u.h[3] = pkrtz(kx1[it].z, kx1[it].w);                                  \
      *(f16x8*)&Ks[SW64(j >> 3, (j & 7) * 8)] = u.v;                         \
    }                                                                        \
    _Pragma("unroll")                                                        \
    for (int it = 0; it < 2; ++it) {                                         \
      U8 u;                                                                  \
      u.h[0] = pkrtz(vv[it][0], vv[it][1]);                                  \
      u.h[1] = pkrtz(vv[it][2], vv[it][3]);                                  \
      u.h[2] = pkrtz(vv[it][4], vv[it][5]);                                  \
      u.h[3] = pkrtz(vv[it][6], vv[it][7]);                                  \
      *(f16x8*)&VTs[it][SW64(tid & 63, (tid >> 6) * 8)] = u.v;               \
    }                                                                        \
  }

  // softmax for one half: exp2, VALU l-sum, pack PV A-frags (key-permuted)
#define SOFTMAX(SF, PF)                                                      \
  {                                                                          \
    _Pragma("unroll")                                                        \
    for (int mi = 0; mi < 2; ++mi) {                                         \
      float p[4][4];                                                         \
      _Pragma("unroll")                                                      \
      for (int nj = 0; nj < 4; ++nj)                                         \
        _Pragma("unroll")                                                    \
        for (int rg = 0; rg < 4; ++rg)                                       \
          p[nj][rg] = __builtin_amdgcn_exp2f(SF[mi][nj][rg]);                \
      _Pragma("unroll")                                                      \
      for (int kk = 0; kk < 2; ++kk) {                                       \
        U8 u;                                                                \
        u.h[0] = pkrtz(p[kk][0], p[kk][1]);                                  \
        u.h[1] = pkrtz(p[kk][2], p[kk][3]);                                  \
        u.h[2] = pkrtz(p[kk + 2][0], p[kk + 2][1]);                          \
        u.h[3] = pkrtz(p[kk + 2][2], p[kk + 2][3]);                          \
        PF[mi][kk] = u.v;                                                    \
      }                                                                      \
      l_acc[mi] += ((p[0][0] + p[0][1]) + (p[0][2] + p[0][3])) +             \
                   ((p[1][0] + p[1][1]) + (p[1][2] + p[1][3])) +             \
                   ((p[2][0] + p[2][1]) + (p[2][2] + p[2][3])) +             \
                   ((p[3][0] + p[3][1]) + (p[3][2] + p[3][3]));              \
    }                                                                        \
  }

  KV_ISSUE(0)  // prologue: round 0 loads in flight

  for (int t = 0; t < NR; ++t) {
    const int kv0 = t * KVR;
    if (t) __syncthreads();  // prior round LDS reads done before overwrite

    STAGE_WRITE()
    if (t < NR - 1) KV_ISSUE(kv0 + KVR)
    __syncthreads();

    // ================= two-half software pipeline =================
    // --- QK0 ---
    f32x4 sf0[2][4];
#pragma unroll
    for (int nj = 0; nj < 4; ++nj) {
      f32x4 bv = *(const f32x4*)&biasS[kv0 + nj * 16 + g * 4];
      sf0[0][nj] = bv; sf0[1][nj] = bv;
    }
    __builtin_amdgcn_s_setprio(1);
#pragma unroll
    for (int nj = 0; nj < 4; ++nj)
#pragma unroll
      for (int kk = 0; kk < 2; ++kk) {
        f16x8 kf = *(const f16x8*)&Ks[SW64(nj * 16 + r, kk * 32 + g * 8)];
        sf0[0][nj] = MFMA16(kf, qf[0][kk], sf0[0][nj]);
        sf0[1][nj] = MFMA16(kf, qf[1][kk], sf0[1][nj]);
      }
    __builtin_amdgcn_s_setprio(0);

    // --- SM0 (VALU; overlaps QK0 drain) ---
    f16x8 pf0[2][2];
    SOFTMAX(sf0, pf0)

    // --- QK1 (MFMA; independent of SM0/PV0 — issues while SM0 retires) ---
    f32x4 sf1[2][4];
#pragma unroll
    for (int nj = 0; nj < 4; ++nj) {
      f32x4 bv = *(const f32x4*)&biasS[kv0 + 64 + nj * 16 + g * 4];
      sf1[0][nj] = bv; sf1[1][nj] = bv;
    }
    __builtin_amdgcn_s_setprio(1);
#pragma unroll
    for (int nj = 0; nj < 4; ++nj)
#pragma unroll
      for (int kk = 0; kk < 2; ++kk) {
        f16x8 kf = *(const f16x8*)&Ks[SW64(64 + nj * 16 + r, kk * 32 + g * 8)];
        sf1[0][nj] = MFMA16(kf, qf[0][kk], sf1[0][nj]);
        sf1[1][nj] = MFMA16(kf, qf[1][kk], sf1[1][nj]);
      }

    // --- PV0 (MFMA; SM1's VALU will overlap these) ---
#pragma unroll
    for (int kk = 0; kk < 2; ++kk)
#pragma unroll
      for (int nj = 0; nj < 4; ++nj) {
        f16x8 vf = *(const f16x8*)&VTs[0][SW64(nj * 16 + r, kk * 32 + g * 8)];
        oacc[0][nj] = MFMA16(pf0[0][kk], vf, oacc[0][nj]);
        oacc[1][nj] = MFMA16(pf0[1][kk], vf, oacc[1][nj]);
      }
    __builtin_amdgcn_s_setprio(0);

    // --- SM1 (VALU; overlaps PV0 MFMAs) ---
    f16x8 pf1[2][2];
    SOFTMAX(sf1, pf1)

    // --- PV1 ---
    __builtin_amdgcn_s_setprio(1);
#pragma unroll
    for (int kk = 0; kk < 2; ++kk)
#pragma unroll
      for (int nj = 0; nj < 4; ++nj) {
        f16x8 vf = *(const f16x8*)&VTs[1][SW64(nj * 16 + r, kk * 32 + g * 8)];
        oacc[0][nj] = MFMA16(pf1[0][kk], vf, oacc[0][nj]);
        oacc[1][nj] = MFMA16(pf1[1][kk], vf, oacc[1][nj]);
      }
    __builtin_amdgcn_s_setprio(0);
  }

  // ---- epilogue: cross-lane l reduce (once), redistribute 1/l from
  // softmax layout (q=r) to output layout (q=g*4+rg), store fp32 ----
  float* ob = out + ((size_t)ec * Hh + h) * (size_t)Ss * Dd;
#pragma unroll
  for (int mi = 0; mi < 2; ++mi) {
    float rs = l_acc[mi];
    rs += __shfl_xor(rs, 16);
    rs += __shfl_xor(rs, 32);
    float linv = 1.0f / rs;
    float i4[4];
#pragma unroll
    for (int rg = 0; rg < 4; ++rg) i4[rg] = __shfl(linv, g * 4 + rg, 16);
#pragma unroll
    for (int nj = 0; nj < 4; ++nj)
#pragma unroll
      for (int rg = 0; rg < 4; ++rg) {
        int row = q0 + mi * 16 + g * 4 + rg;
        int dim = nj * 16 + r;
        ob[(size_t)row * Dd + dim] = oacc[mi][nj][rg] * i4[rg];
      }
  }
}

extern "C" void kernel_launch(void* const* d_in, const int* in_sizes, int n_in,
                              void* d_out, int out_size, void* d_ws, size_t ws_size,
                              hipStream_t stream) {
  const float* Q    = (const float*)d_in[0];
  const float* K    = (const float*)d_in[1];
  const float* V    = (const float*)d_in[2];
  const int*   idx  = (const int*)d_in[3];
  const float* mask = (const float*)d_in[4];
  float* out = (float*)d_out;
  dim3 grid(1024), block(512);
  hipLaunchKernelGGL(sparse_attn_kernel, grid, block, 0, stream,
                     Q, K, V, idx, mask, out);
}

// Round 15
// 60.769 us; speedup vs baseline: 2.1783x; 2.1783x over previous
//
#include <hip/hip_runtime.h>
#include <math.h>

// SparseAttention: E=8 experts x CAP=4 routed batches, full attention over
// [H=16, S=512, D=64] with key mask bias. fp32 in/out, fp16 MFMA compute.
// R15 = R12 base (best-measured structure; R14's 2-sf pipeline spilled at
// VGPR=128) with REGISTER-NEUTRAL PHASE MIXING: staging split by operand
// lifetime. Ks frees after QK, VTs frees after PV, so:
//   Phase A: STAGE_V(t) || QK(t) || SM(t) || issue V-loads(t+1) -> bar
//   Phase B: PV(t) || STAGE_K(t+1) || issue K-loads(t+2)        -> bar
// Every phase mixes LDS-write/LDS-read/MFMA/VALU (m201 role-mixing at
// 2-phase cost). Same barrier count, same prefetch registers as R12; only
// pf (16 VGPR) crosses a barrier. Keeps: in-register P->PV key permutation
// (0 conflicts), ones-MFMA denominator, bias precomputed in LDS,
// sibling-XCD swizzle, fixed-ref softmax, setprio, 512-thr blocks QB=256.

typedef _Float16 f16x8 __attribute__((ext_vector_type(8)));
typedef _Float16 f16x2 __attribute__((ext_vector_type(2)));
typedef float    f32x4 __attribute__((ext_vector_type(4)));

#define MFMA16(a, b, c) __builtin_amdgcn_mfma_f32_16x16x32_f16((a), (b), (c), 0, 0, 0)

constexpr int Hh = 16;
constexpr int Ss = 512;
constexpr int Dd = 64;
constexpr int QB = 256;       // query rows per workgroup (8 waves x 32)
constexpr int KVB = 64;       // key tile
constexpr int NT = Ss / KVB;  // 8 tiles
constexpr float QS = 0.125f * 1.44269504088896f;      // scale*log2e in Q
constexpr float BM = 1000000.0f * 1.44269504088896f;  // penalty * log2e

union U8 { f16x8 v; f16x2 h[4]; };

// Swizzled half-index in a [rows][64 half cols] tile (row stride 128B).
__device__ __forceinline__ int SW(int row, int col) {
  return row * 64 + (col ^ ((row & 7) << 3));
}

__device__ __forceinline__ f16x2 pkrtz(float a, float b) {
  auto t = __builtin_amdgcn_cvt_pkrtz(a, b);
  return *(f16x2*)&t;
}

__global__ __launch_bounds__(512) void sparse_attn_kernel(
    const float* __restrict__ Q, const float* __restrict__ K,
    const float* __restrict__ V, const int* __restrict__ idx,
    const float* __restrict__ mask, float* __restrict__ out) {
  const int tid  = threadIdx.x;
  const int lane = tid & 63;
  const int wv   = tid >> 6;        // wave 0..7
  const int r    = lane & 15;       // MFMA 16-lane index
  const int g    = lane >> 4;       // MFMA 4-group 0..3

  // Sibling-XCD swizzle (bijective): the 2 qb siblings of one (ec,h) share
  // phys%8 -> same XCD, 8 dispatch slots apart -> K/V L2-deduped.
  const int phys = blockIdx.x;       // 1024
  const int G    = (phys & 7) | ((phys >> 4) << 3);
  const int qb   = (phys >> 3) & 1;
  const int h    = G & 15;
  const int ec   = G >> 4;
  const int b    = idx[ec];

  __shared__ _Float16 Ks[64 * 64];      // [key][dim] swizzled
  __shared__ _Float16 VTs[64 * 64];     // [dim][perm-key] swizzled
  __shared__ float    biasS[Ss];        // precomputed bias row (m*BM - BM)

  const size_t bh = ((size_t)b * Hh + h) * (size_t)Ss * Dd;
  const float* Qb = Q + bh;
  const float* Kb = K + bh;
  const float* Vb = V + bh;
  const float* mrow = mask + (size_t)b * Ss;

  // ---- prologue: precompute bias row into LDS (1 float/thread) ----
  biasS[tid] = mrow[tid] * BM - BM;

  const int q0 = qb * QB + wv * 32;

  // ---- Q fragments, pre-scaled (B-operand: col=lane%16 -> q row) ----
  f16x8 qf[2][2];
#pragma unroll
  for (int mi = 0; mi < 2; ++mi)
#pragma unroll
    for (int kk = 0; kk < 2; ++kk) {
      const float* qp = Qb + (size_t)(q0 + mi * 16 + r) * Dd + kk * 32 + g * 8;
      float4 x0 = *(const float4*)qp;
      float4 x1 = *(const float4*)(qp + 4);
      U8 u;
      u.h[0] = pkrtz(x0.x * QS, x0.y * QS);
      u.h[1] = pkrtz(x0.z * QS, x0.w * QS);
      u.h[2] = pkrtz(x1.x * QS, x1.y * QS);
      u.h[3] = pkrtz(x1.z * QS, x1.w * QS);
      qf[mi][kk] = u.v;
    }

  // ones B-operand for the row-sum MFMA (l = P * 1)
  f16x8 ones;
#pragma unroll
  for (int e = 0; e < 8; ++e) ones[e] = (_Float16)1.0f;

  f32x4 oacc[2][4];
#pragma unroll
  for (int mi = 0; mi < 2; ++mi)
#pragma unroll
    for (int nj = 0; nj < 4; ++nj) oacc[mi][nj] = (f32x4){0.f, 0.f, 0.f, 0.f};
  f32x4 lacc[2] = {(f32x4){0.f, 0.f, 0.f, 0.f}, (f32x4){0.f, 0.f, 0.f, 0.f}};

  // ---- prefetch registers (operand-split in time; no duplication) ----
  float4 kx0, kx1;   // K tile in flight  (8 VGPR)
  float  vv[8];      // V tile in flight  (8 VGPR)

  // K map: tid -> krow=tid>>3 (0..63), dg8=tid&7 (16B group).
  // V map: thread (oct=tid>>6, dim=tid&63); oct=(kk,g2): loads phys keys
  // 16kk+4g2+{0..3} and +32 so VTs col kk*32+8g2+j holds phys key
  // (kk+2*(j>>2))*16+g2*4+(j&3) — matches QK^T D-layout (P stays in regs).
#define K_ISSUE(KV0)                                                         \
  {                                                                          \
    const float* kp_ = Kb + (size_t)((KV0) + (tid >> 3)) * Dd + (tid & 7) * 8;\
    kx0 = *(const float4*)kp_;                                               \
    kx1 = *(const float4*)(kp_ + 4);                                         \
  }

#define V_ISSUE(KV0)                                                         \
  {                                                                          \
    int oct = tid >> 6;                                                      \
    int kb1 = (oct >> 2) * 16 + (oct & 3) * 4;                               \
    const float* vp = Vb + (size_t)((KV0) + kb1) * Dd + (tid & 63);          \
    _Pragma("unroll")                                                        \
    for (int jj = 0; jj < 4; ++jj) {                                         \
      vv[jj]     = vp[(size_t)jj * Dd];                                      \
      vv[jj + 4] = vp[(size_t)(jj + 32) * Dd];                               \
    }                                                                        \
  }

#define STAGE_K()                                                            \
  {                                                                          \
    U8 u;                                                                    \
    u.h[0] = pkrtz(kx0.x, kx0.y);                                            \
    u.h[1] = pkrtz(kx0.z, kx0.w);                                            \
    u.h[2] = pkrtz(kx1.x, kx1.y);                                            \
    u.h[3] = pkrtz(kx1.z, kx1.w);                                            \
    *(f16x8*)&Ks[SW(tid >> 3, (tid & 7) * 8)] = u.v;                         \
  }

#define STAGE_V()                                                            \
  {                                                                          \
    U8 u2;                                                                   \
    u2.h[0] = pkrtz(vv[0], vv[1]);                                           \
    u2.h[1] = pkrtz(vv[2], vv[3]);                                           \
    u2.h[2] = pkrtz(vv[4], vv[5]);                                           \
    u2.h[3] = pkrtz(vv[6], vv[7]);                                           \
    *(f16x8*)&VTs[SW(tid & 63, (tid >> 6) * 8)] = u2.v;                      \
  }

  // ---- prologue: Ks <- K(0); kx <- K(1); vv <- V(0) ----
  K_ISSUE(0)
  V_ISSUE(0)
  STAGE_K()
  K_ISSUE(KVB)
  __syncthreads();

  for (int t = 0; t < NT; ++t) {
    const int kv0 = t * KVB;

    // ================= Phase A: STAGE_V(t) || QK(t) || SM(t) =================
    STAGE_V()                     // consumes vv = V(t)
    if (t < NT - 1) V_ISSUE(kv0 + KVB)   // vv <- V(t+1), lands under B+A

    f32x4 sf[2][4];
#pragma unroll
    for (int nj = 0; nj < 4; ++nj) {
      f32x4 bv = *(const f32x4*)&biasS[kv0 + nj * 16 + g * 4];
      sf[0][nj] = bv; sf[1][nj] = bv;
    }
    __builtin_amdgcn_s_setprio(1);
#pragma unroll
    for (int nj = 0; nj < 4; ++nj)
#pragma unroll
      for (int kk = 0; kk < 2; ++kk) {
        f16x8 kf = *(const f16x8*)&Ks[SW(nj * 16 + r, kk * 32 + g * 8)];
        sf[0][nj] = MFMA16(kf, qf[0][kk], sf[0][nj]);
        sf[1][nj] = MFMA16(kf, qf[1][kk], sf[1][nj]);
      }
    __builtin_amdgcn_s_setprio(0);

    // softmax numerators (fixed ref 0) packed directly into PV A-frags
    // (key permutation baked into VTs)
    f16x8 pf[2][2];
#pragma unroll
    for (int mi = 0; mi < 2; ++mi) {
      float p[4][4];
#pragma unroll
      for (int nj = 0; nj < 4; ++nj)
#pragma unroll
        for (int rg = 0; rg < 4; ++rg)
          p[nj][rg] = __builtin_amdgcn_exp2f(sf[mi][nj][rg]);
#pragma unroll
      for (int kk = 0; kk < 2; ++kk) {
        U8 u;
        u.h[0] = pkrtz(p[kk][0], p[kk][1]);
        u.h[1] = pkrtz(p[kk][2], p[kk][3]);
        u.h[2] = pkrtz(p[kk + 2][0], p[kk + 2][1]);
        u.h[3] = pkrtz(p[kk + 2][2], p[kk + 2][3]);
        pf[mi][kk] = u.v;
      }
    }
    __syncthreads();   // VTs(t) complete for PV; Ks reads done for STAGE_K

    // ================= Phase B: PV(t) || STAGE_K(t+1) =================
    __builtin_amdgcn_s_setprio(1);
#pragma unroll
    for (int kk = 0; kk < 2; ++kk) {
      lacc[0] = MFMA16(pf[0][kk], ones, lacc[0]);
      lacc[1] = MFMA16(pf[1][kk], ones, lacc[1]);
#pragma unroll
      for (int nj = 0; nj < 4; ++nj) {
        f16x8 vf = *(const f16x8*)&VTs[SW(nj * 16 + r, kk * 32 + g * 8)];
        oacc[0][nj] = MFMA16(pf[0][kk], vf, oacc[0][nj]);
        oacc[1][nj] = MFMA16(pf[1][kk], vf, oacc[1][nj]);
      }
    }
    __builtin_amdgcn_s_setprio(0);

    if (t < NT - 1) {
      STAGE_K()                        // Ks <- K(t+1) (consumes kx)
      if (t < NT - 2) K_ISSUE(kv0 + 2 * KVB)   // kx <- K(t+2)
      __syncthreads(); // Ks(t+1) ready; PV reads done before next STAGE_V
    }
  }

  // ---- epilogue: lacc already in oacc row layout (D rows = g*4+rg) — no
  // cross-lane redistribution needed. Divide and store fp32. ----
  float* ob = out + ((size_t)ec * Hh + h) * (size_t)Ss * Dd;
#pragma unroll
  for (int mi = 0; mi < 2; ++mi) {
    float i4[4];
#pragma unroll
    for (int rg = 0; rg < 4; ++rg) i4[rg] = 1.0f / lacc[mi][rg];
#pragma unroll
    for (int nj = 0; nj < 4; ++nj)
#pragma unroll
      for (int rg = 0; rg < 4; ++rg) {
        int row = q0 + mi * 16 + g * 4 + rg;
        int dim = nj * 16 + r;
        ob[(size_t)row * Dd + dim] = oacc[mi][nj][rg] * i4[rg];
      }
  }
}

extern "C" void kernel_launch(void* const* d_in, const int* in_sizes, int n_in,
                              void* d_out, int out_size, void* d_ws, size_t ws_size,
                              hipStream_t stream) {
  const float* Q    = (const float*)d_in[0];
  const float* K    = (const float*)d_in[1];
  const float* V    = (const float*)d_in[2];
  const int*   idx  = (const int*)d_in[3];
  const float* mask = (const float*)d_in[4];
  float* out = (float*)d_out;
  dim3 grid(1024), block(512);
  hipLaunchKernelGGL(sparse_attn_kernel, grid, block, 0, stream,
                     Q, K, V, idx, mask, out);
}

// Round 16
// 60.339 us; speedup vs baseline: 2.1938x; 1.0071x over previous
//
#include <hip/hip_runtime.h>
#include <math.h>

// SparseAttention: E=8 experts x CAP=4 routed batches, full attention over
// [H=16, S=512, D=64] with key mask bias. fp32 in/out, fp16 MFMA compute.
// R16 = R15 with SM moved across the barrier into phase B (phase balance):
//   Phase A: STAGE_V(t) || QK(t) || issue V-loads(t+1)            -> bar
//   Phase B: SM(t) || PV(t) || STAGE_K(t+1) || issue K-loads(t+2) -> bar
// A = {LDS-write, LDS-read, MFMA}; B = {VALU, MFMA, LDS-read/write}: the
// two antiphase resident blocks now always have complementary pipe demand.
// sf (32 VGPR) crosses the barrier instead of pf (16): ~90 VGPR, same
// 4-waves/SIMD band. Keeps: in-register P->PV key permutation (0 bank
// conflicts), ones-MFMA denominator, bias precomputed in LDS, sibling-XCD
// swizzle, fixed-ref softmax, setprio, 512-thr blocks QB=256.

typedef _Float16 f16x8 __attribute__((ext_vector_type(8)));
typedef _Float16 f16x2 __attribute__((ext_vector_type(2)));
typedef float    f32x4 __attribute__((ext_vector_type(4)));

#define MFMA16(a, b, c) __builtin_amdgcn_mfma_f32_16x16x32_f16((a), (b), (c), 0, 0, 0)

constexpr int Hh = 16;
constexpr int Ss = 512;
constexpr int Dd = 64;
constexpr int QB = 256;       // query rows per workgroup (8 waves x 32)
constexpr int KVB = 64;       // key tile
constexpr int NT = Ss / KVB;  // 8 tiles
constexpr float QS = 0.125f * 1.44269504088896f;      // scale*log2e in Q
constexpr float BM = 1000000.0f * 1.44269504088896f;  // penalty * log2e

union U8 { f16x8 v; f16x2 h[4]; };

// Swizzled half-index in a [rows][64 half cols] tile (row stride 128B).
__device__ __forceinline__ int SW(int row, int col) {
  return row * 64 + (col ^ ((row & 7) << 3));
}

__device__ __forceinline__ f16x2 pkrtz(float a, float b) {
  auto t = __builtin_amdgcn_cvt_pkrtz(a, b);
  return *(f16x2*)&t;
}

__global__ __launch_bounds__(512) void sparse_attn_kernel(
    const float* __restrict__ Q, const float* __restrict__ K,
    const float* __restrict__ V, const int* __restrict__ idx,
    const float* __restrict__ mask, float* __restrict__ out) {
  const int tid  = threadIdx.x;
  const int lane = tid & 63;
  const int wv   = tid >> 6;        // wave 0..7
  const int r    = lane & 15;       // MFMA 16-lane index
  const int g    = lane >> 4;       // MFMA 4-group 0..3

  // Sibling-XCD swizzle (bijective): the 2 qb siblings of one (ec,h) share
  // phys%8 -> same XCD, 8 dispatch slots apart -> K/V L2-deduped.
  const int phys = blockIdx.x;       // 1024
  const int G    = (phys & 7) | ((phys >> 4) << 3);
  const int qb   = (phys >> 3) & 1;
  const int h    = G & 15;
  const int ec   = G >> 4;
  const int b    = idx[ec];

  __shared__ _Float16 Ks[64 * 64];      // [key][dim] swizzled
  __shared__ _Float16 VTs[64 * 64];     // [dim][perm-key] swizzled
  __shared__ float    biasS[Ss];        // precomputed bias row (m*BM - BM)

  const size_t bh = ((size_t)b * Hh + h) * (size_t)Ss * Dd;
  const float* Qb = Q + bh;
  const float* Kb = K + bh;
  const float* Vb = V + bh;
  const float* mrow = mask + (size_t)b * Ss;

  // ---- prologue: precompute bias row into LDS (1 float/thread) ----
  biasS[tid] = mrow[tid] * BM - BM;

  const int q0 = qb * QB + wv * 32;

  // ---- Q fragments, pre-scaled (B-operand: col=lane%16 -> q row) ----
  f16x8 qf[2][2];
#pragma unroll
  for (int mi = 0; mi < 2; ++mi)
#pragma unroll
    for (int kk = 0; kk < 2; ++kk) {
      const float* qp = Qb + (size_t)(q0 + mi * 16 + r) * Dd + kk * 32 + g * 8;
      float4 x0 = *(const float4*)qp;
      float4 x1 = *(const float4*)(qp + 4);
      U8 u;
      u.h[0] = pkrtz(x0.x * QS, x0.y * QS);
      u.h[1] = pkrtz(x0.z * QS, x0.w * QS);
      u.h[2] = pkrtz(x1.x * QS, x1.y * QS);
      u.h[3] = pkrtz(x1.z * QS, x1.w * QS);
      qf[mi][kk] = u.v;
    }

  // ones B-operand for the row-sum MFMA (l = P * 1)
  f16x8 ones;
#pragma unroll
  for (int e = 0; e < 8; ++e) ones[e] = (_Float16)1.0f;

  f32x4 oacc[2][4];
#pragma unroll
  for (int mi = 0; mi < 2; ++mi)
#pragma unroll
    for (int nj = 0; nj < 4; ++nj) oacc[mi][nj] = (f32x4){0.f, 0.f, 0.f, 0.f};
  f32x4 lacc[2] = {(f32x4){0.f, 0.f, 0.f, 0.f}, (f32x4){0.f, 0.f, 0.f, 0.f}};

  // ---- prefetch registers (operand-split in time; no duplication) ----
  float4 kx0, kx1;   // K tile in flight  (8 VGPR)
  float  vv[8];      // V tile in flight  (8 VGPR)

  // K map: tid -> krow=tid>>3 (0..63), dg8=tid&7 (16B group).
  // V map: thread (oct=tid>>6, dim=tid&63); oct=(kk,g2): loads phys keys
  // 16kk+4g2+{0..3} and +32 so VTs col kk*32+8g2+j holds phys key
  // (kk+2*(j>>2))*16+g2*4+(j&3) — matches QK^T D-layout (P stays in regs).
#define K_ISSUE(KV0)                                                         \
  {                                                                          \
    const float* kp_ = Kb + (size_t)((KV0) + (tid >> 3)) * Dd + (tid & 7) * 8;\
    kx0 = *(const float4*)kp_;                                               \
    kx1 = *(const float4*)(kp_ + 4);                                         \
  }

#define V_ISSUE(KV0)                                                         \
  {                                                                          \
    int oct = tid >> 6;                                                      \
    int kb1 = (oct >> 2) * 16 + (oct & 3) * 4;                               \
    const float* vp = Vb + (size_t)((KV0) + kb1) * Dd + (tid & 63);          \
    _Pragma("unroll")                                                        \
    for (int jj = 0; jj < 4; ++jj) {                                         \
      vv[jj]     = vp[(size_t)jj * Dd];                                      \
      vv[jj + 4] = vp[(size_t)(jj + 32) * Dd];                               \
    }                                                                        \
  }

#define STAGE_K()                                                            \
  {                                                                          \
    U8 u;                                                                    \
    u.h[0] = pkrtz(kx0.x, kx0.y);                                            \
    u.h[1] = pkrtz(kx0.z, kx0.w);                                            \
    u.h[2] = pkrtz(kx1.x, kx1.y);                                            \
    u.h[3] = pkrtz(kx1.z, kx1.w);                                            \
    *(f16x8*)&Ks[SW(tid >> 3, (tid & 7) * 8)] = u.v;                         \
  }

#define STAGE_V()                                                            \
  {                                                                          \
    U8 u2;                                                                   \
    u2.h[0] = pkrtz(vv[0], vv[1]);                                           \
    u2.h[1] = pkrtz(vv[2], vv[3]);                                           \
    u2.h[2] = pkrtz(vv[4], vv[5]);                                           \
    u2.h[3] = pkrtz(vv[6], vv[7]);                                           \
    *(f16x8*)&VTs[SW(tid & 63, (tid >> 6) * 8)] = u2.v;                      \
  }

  // ---- prologue: Ks <- K(0); kx <- K(1); vv <- V(0) ----
  K_ISSUE(0)
  V_ISSUE(0)
  STAGE_K()
  K_ISSUE(KVB)
  __syncthreads();

  for (int t = 0; t < NT; ++t) {
    const int kv0 = t * KVB;

    // ============ Phase A: STAGE_V(t) || QK(t) || V-loads(t+1) ============
    STAGE_V()                            // consumes vv = V(t)
    if (t < NT - 1) V_ISSUE(kv0 + KVB)   // vv <- V(t+1), lands under A+B

    f32x4 sf[2][4];
#pragma unroll
    for (int nj = 0; nj < 4; ++nj) {
      f32x4 bv = *(const f32x4*)&biasS[kv0 + nj * 16 + g * 4];
      sf[0][nj] = bv; sf[1][nj] = bv;
    }
    __builtin_amdgcn_s_setprio(1);
#pragma unroll
    for (int nj = 0; nj < 4; ++nj)
#pragma unroll
      for (int kk = 0; kk < 2; ++kk) {
        f16x8 kf = *(const f16x8*)&Ks[SW(nj * 16 + r, kk * 32 + g * 8)];
        sf[0][nj] = MFMA16(kf, qf[0][kk], sf[0][nj]);
        sf[1][nj] = MFMA16(kf, qf[1][kk], sf[1][nj]);
      }
    __builtin_amdgcn_s_setprio(0);
    __syncthreads();   // VTs(t) complete for PV; Ks(t) reads done for STAGE_K

    // ====== Phase B: SM(t) || PV(t) || STAGE_K(t+1) || K-loads(t+2) ======
    f16x8 pf[2][2];
#pragma unroll
    for (int mi = 0; mi < 2; ++mi) {
      float p[4][4];
#pragma unroll
      for (int nj = 0; nj < 4; ++nj)
#pragma unroll
        for (int rg = 0; rg < 4; ++rg)
          p[nj][rg] = __builtin_amdgcn_exp2f(sf[mi][nj][rg]);
#pragma unroll
      for (int kk = 0; kk < 2; ++kk) {
        U8 u;
        u.h[0] = pkrtz(p[kk][0], p[kk][1]);
        u.h[1] = pkrtz(p[kk][2], p[kk][3]);
        u.h[2] = pkrtz(p[kk + 2][0], p[kk + 2][1]);
        u.h[3] = pkrtz(p[kk + 2][2], p[kk + 2][3]);
        pf[mi][kk] = u.v;
      }
    }

    __builtin_amdgcn_s_setprio(1);
#pragma unroll
    for (int kk = 0; kk < 2; ++kk) {
      lacc[0] = MFMA16(pf[0][kk], ones, lacc[0]);
      lacc[1] = MFMA16(pf[1][kk], ones, lacc[1]);
#pragma unroll
      for (int nj = 0; nj < 4; ++nj) {
        f16x8 vf = *(const f16x8*)&VTs[SW(nj * 16 + r, kk * 32 + g * 8)];
        oacc[0][nj] = MFMA16(pf[0][kk], vf, oacc[0][nj]);
        oacc[1][nj] = MFMA16(pf[1][kk], vf, oacc[1][nj]);
      }
    }
    __builtin_amdgcn_s_setprio(0);

    if (t < NT - 1) {
      STAGE_K()                                // Ks <- K(t+1) (consumes kx)
      if (t < NT - 2) K_ISSUE(kv0 + 2 * KVB)   // kx <- K(t+2)
      __syncthreads();  // Ks(t+1) ready; VTs(t) reads done before next STAGE_V
    }
  }

  // ---- epilogue: lacc already in oacc row layout (D rows = g*4+rg) — no
  // cross-lane redistribution needed. Divide and store fp32. ----
  float* ob = out + ((size_t)ec * Hh + h) * (size_t)Ss * Dd;
#pragma unroll
  for (int mi = 0; mi < 2; ++mi) {
    float i4[4];
#pragma unroll
    for (int rg = 0; rg < 4; ++rg) i4[rg] = 1.0f / lacc[mi][rg];
#pragma unroll
    for (int nj = 0; nj < 4; ++nj)
#pragma unroll
      for (int rg = 0; rg < 4; ++rg) {
        int row = q0 + mi * 16 + g * 4 + rg;
        int dim = nj * 16 + r;
        ob[(size_t)row * Dd + dim] = oacc[mi][nj][rg] * i4[rg];
      }
  }
}

extern "C" void kernel_launch(void* const* d_in, const int* in_sizes, int n_in,
                              void* d_out, int out_size, void* d_ws, size_t ws_size,
                              hipStream_t stream) {
  const float* Q    = (const float*)d_in[0];
  const float* K    = (const float*)d_in[1];
  const float* V    = (const float*)d_in[2];
  const int*   idx  = (const int*)d_in[3];
  const float* mask = (const float*)d_in[4];
  float* out = (float*)d_out;
  dim3 grid(1024), block(512);
  hipLaunchKernelGGL(sparse_attn_kernel, grid, block, 0, stream,
                     Q, K, V, idx, mask, out);
}